// Round 9
// baseline (369.505 us; speedup 1.0000x reference)
//
#include <hip/hip_runtime.h>
#include <hip/hip_bf16.h>

#define B_ 2
#define S_ 2048
#define E_ 2048
#define H_ 32
#define M_ (B_*S_)   /* 4096 rows total */

typedef __bf16 bf16x8 __attribute__((ext_vector_type(8)));
typedef float  f32x4  __attribute__((ext_vector_type(4)));

__device__ __forceinline__ ushort f2bf(float f) {
    uint u = __float_as_uint(f);
    u += 0x7fffu + ((u >> 16) & 1u);   // RNE
    return (ushort)(u >> 16);
}
__device__ __forceinline__ uint pack2bf(float a, float b) {   // v_cvt_pk_bf16_f32
    __hip_bfloat162 h = __float22bfloat162_rn(make_float2(a, b));
    return *(uint*)&h;
}
__device__ __forceinline__ float fexp2(float x) {             // raw v_exp_f32
#if __has_builtin(__builtin_amdgcn_exp2f)
    return __builtin_amdgcn_exp2f(x);
#else
    return exp2f(x);
#endif
}
__device__ __forceinline__ f32x4 f4zero() {
    f32x4 z; z[0]=0.f; z[1]=0.f; z[2]=0.f; z[3]=0.f; return z;
}
// async global->LDS 16B: lds dest is wave-uniform base; HW scatters lane i to base+16*i
__device__ __forceinline__ void async16(const ushort* g, ushort* l) {
    __builtin_amdgcn_global_load_lds((const __attribute__((address_space(1))) void*)g,
                                     (__attribute__((address_space(3))) void*)l, 16, 0, 0);
}

// ---------- prep: cast x (f32->bf16) + transpose/cast 4 weights, one launch ----------
#define NCAST ((M_*E_)/1024)
__global__ __launch_bounds__(256) void prep_kernel(const float* __restrict__ x, ushort* __restrict__ xb,
        const float* __restrict__ W0, const float* __restrict__ W1,
        const float* __restrict__ W2, const float* __restrict__ W3,
        ushort* __restrict__ T0, ushort* __restrict__ T1,
        ushort* __restrict__ T2, ushort* __restrict__ T3) {
    const int bid = blockIdx.x;
    if (bid < NCAST) {              // ---- cast path: 4 f32 -> 4 bf16 per thread
        int i = (bid * 256 + threadIdx.x) * 4;
        float4 v = *(const float4*)(x + i);
        uint2 o;
        o.x = pack2bf(v.x, v.y);
        o.y = pack2bf(v.z, v.w);
        *(uint2*)(xb + i) = o;
        return;
    }
    // ---- wtrans path: W[k][n] f32 -> Wt[n][k] bf16
    const int wb = bid - NCAST;     // 0..4095
    const int z  = wb >> 10;
    const int rem = wb & 1023;
    const float* W = (z==0)?W0:(z==1)?W1:(z==2)?W2:W3;
    ushort*      T = (z==0)?T0:(z==1)?T1:(z==2)?T2:T3;
    __shared__ float tile[64][65];
    const int k0 = (rem >> 5) * 64, n0 = (rem & 31) * 64;
    const int rr = threadIdx.x >> 4;          // 0..15
    const int cc = (threadIdx.x & 15) * 4;    // 0..60
    #pragma unroll
    for (int p = 0; p < 4; ++p) {
        int r = p * 16 + rr;
        float4 v = *(const float4*)(W + (size_t)(k0 + r) * E_ + n0 + cc);
        tile[r][cc+0] = v.x; tile[r][cc+1] = v.y; tile[r][cc+2] = v.z; tile[r][cc+3] = v.w;
    }
    __syncthreads();
    #pragma unroll
    for (int p = 0; p < 4; ++p) {
        int rn = p * 16 + rr;
        uint2 o;
        o.x = pack2bf(tile[cc+0][rn], tile[cc+1][rn]);
        o.y = pack2bf(tile[cc+2][rn], tile[cc+3][rn]);
        *(uint2*)(T + (size_t)(n0 + rn) * E_ + k0 + cc) = o;
    }
}

// ========== 128x256 bf16 MFMA GEMM, read-ahead pipeline (r8: Q+K proj) ==========
// r8 model: at 256^2 the phase is SERIAL {LDS reads ~1150cy; MFMA ~1241cy} ->
// MfmaUtil 37%. Fix: overlap by reading phase t+1's fragments DURING t's MFMA
// cluster. Needs dbuf operand regs: 128x256 tile -> per-wave 64x64 (acc 64 VGPR)
// + 2x(pa 32 + pb 32) = ~192 VGPR, fits 256 budget at 2 waves/SIMD.
// 512 thr = 8 waves (2M x 4N). One phase per K-tile: 32 MFMA, 16 ds_read (next
// tile), 6 global_load_lds. Grid 32x8x2 = 512 blocks = exactly 2 generations.
// Phase t ledger (WAR: stage(t+2)->buf[t&1] safe: t-reads lgkm0-drained before
// t-1's closing barrier. RAW: vmcnt(6) after stage-issue drains t+1's batch
// (6 loads from phase t-1), leaves t+2's 6 in flight; barrier publishes):
//   stage(t+2); VMW6; barrier; read(t+1 frags); MFMA(t regs); lgkm0+schedbar; barrier
#define VMW6 asm volatile("s_waitcnt vmcnt(6)" ::: "memory")
#define VMW0 asm volatile("s_waitcnt vmcnt(0)" ::: "memory")
#define MEMB asm volatile("" ::: "memory")

#define QSTA_(bf, kt) { _Pragma("unroll") for (int it_ = 0; it_ < 2; ++it_) {   \
    async16(A + (size_t)(m0 + it_*64 + srow) * E_ + (kt)*64 + scg*8,            \
            &As[bf][(it_*64 + wave*8) * 64]); } }

#define QSTB_(bf, kt) { _Pragma("unroll") for (int it_ = 0; it_ < 4; ++it_) {   \
    async16(Bt + (size_t)(n0 + it_*64 + srow) * E_ + (kt)*64 + scg*8,           \
            &Bs[bf][(it_*64 + wave*8) * 64]); } }

#define QLOAD_(pa, pb, bf) {                                                    \
    _Pragma("unroll") for (int m_ = 0; m_ < 4; ++m_)                            \
      _Pragma("unroll") for (int k_ = 0; k_ < 2; ++k_) {                        \
        int row_ = wm*64 + m_*16 + l15;                                         \
        pa[m_][k_] = *(const bf16x8*)(&As[bf][row_*64 + (((k_*4 + quad) ^ (row_ & 7)) << 3)]); } \
    _Pragma("unroll") for (int n_ = 0; n_ < 4; ++n_)                            \
      _Pragma("unroll") for (int k_ = 0; k_ < 2; ++k_) {                        \
        int row_ = wn*64 + n_*16 + l15;                                         \
        pb[n_][k_] = *(const bf16x8*)(&Bs[bf][row_*64 + (((k_*4 + quad) ^ (row_ & 7)) << 3)]); } }

#define QMM_(pa, pb) {                                                          \
    __builtin_amdgcn_s_setprio(1);                                              \
    _Pragma("unroll") for (int k_ = 0; k_ < 2; ++k_)                            \
      _Pragma("unroll") for (int m_ = 0; m_ < 4; ++m_)                          \
        _Pragma("unroll") for (int n_ = 0; n_ < 4; ++n_)                        \
          acc[m_][n_] = __builtin_amdgcn_mfma_f32_16x16x32_bf16(                \
              pa[m_][k_], pb[n_][k_], acc[m_][n_], 0, 0, 0);                    \
    __builtin_amdgcn_s_setprio(0);                                              \
  }

// One phase: STG+VM, barrier, prefetch next frags (overlaps MFMA), MFMA, drain, barrier.
#define QPH_(STG, VM, ca, cb, na, nb_, DORD, rdbf) {                            \
    STG; VM;                                                                    \
    MEMB; __builtin_amdgcn_s_barrier();                                         \
    if (DORD) QLOAD_(na, nb_, rdbf);                                            \
    QMM_(ca, cb);                                                               \
    asm volatile("s_waitcnt lgkmcnt(0)" ::: "memory");                          \
    __builtin_amdgcn_sched_barrier(0);                                          \
    MEMB; __builtin_amdgcn_s_barrier(); MEMB;                                   \
  }

template<int NZ>
__global__ __launch_bounds__(512, 2) void gemm_qk(const ushort* __restrict__ A,
        const ushort* __restrict__ Bt0, const ushort* __restrict__ Bt1,
        const float* __restrict__ bias0, const float* __restrict__ bias1,
        void* __restrict__ C0, void* __restrict__ C1) {
    const int bid = blockIdx.x;
    const int z   = bid % NZ;                    // fastest: Q/K share A-tile
    const int nb  = (bid / NZ) % (E_ / 256);
    const int mb  = bid / (NZ * (E_ / 256));

    const ushort* Bt  = (z==0)?Bt0:Bt1;
    const float* bias = (z==0)?bias0:bias1;
    void* Cv          = (z==0)?C0:C1;

    __shared__ ushort As[2][128 * 64];   // 32 KiB
    __shared__ ushort Bs[2][256 * 64];   // 64 KiB

    const int tid  = threadIdx.x;
    const int wave = tid >> 6, lane = tid & 63;
    const int quad = lane >> 4, l15 = lane & 15;
    const int wm = wave >> 2, wn = wave & 3;
    const int m0 = mb * 128, n0 = nb * 256;
    const int srow = tid >> 3;                 // 0..63
    const int scg  = (tid & 7) ^ (srow & 7);   // swizzled source chunk

    f32x4 acc[4][4];
    #pragma unroll
    for (int i = 0; i < 4; ++i)
        #pragma unroll
        for (int j = 0; j < 4; ++j) acc[i][j] = f4zero();

    bf16x8 a0[4][2], b0[4][2], a1[4][2], b1[4][2];   // double-buffered operands

    // prologue: stage T0 -> buf0, T1 -> buf1 (12 instr); drain T0 (6 left); read T0
    QSTA_(0, 0); QSTB_(0, 0);
    QSTA_(1, 1); QSTB_(1, 1);
    VMW6;
    MEMB; __builtin_amdgcn_s_barrier(); MEMB;
    QLOAD_(a0, b0, 0);
    asm volatile("s_waitcnt lgkmcnt(0)" ::: "memory");
    __builtin_amdgcn_sched_barrier(0);
    MEMB; __builtin_amdgcn_s_barrier(); MEMB;

    #pragma unroll 1
    for (int i = 0; i < 15; ++i) {
        // t = 2i:   compute set0 (tile t), prefetch set1 <- buf1 (tile t+1), stage t+2->buf0
        QPH_(QSTA_(0, 2*i + 2); QSTB_(0, 2*i + 2), VMW6, a0, b0, a1, b1, 1, 1);
        // t = 2i+1: compute set1, prefetch set0 <- buf0 (tile t+2... = 2i+2), stage t+3->buf1
        QPH_(QSTA_(1, 2*i + 3); QSTB_(1, 2*i + 3), VMW6, a1, b1, a0, b0, 1, 0);
    }
    // t=30: no stage; drain T31 batch (VMW0); prefetch T31 (buf1); compute T30
    QPH_({}, VMW0, a0, b0, a1, b1, 1, 1);
    // t=31: compute only
    QPH_({}, {}, a1, b1, a0, b0, 0, 0);

    {   // head-wise RoPE epilogue: head = col/64 wave-uniform; x1=acc[m][nt], x2=acc[m][nt+2]
        const float qsc = (z == 0) ? 0.125f * 1.44269504f : 1.0f;  // fold log2e
        const int h = (n0 + wn * 64) >> 6;
        float sn[2], cs[2];
        #pragma unroll
        for (int nt = 0; nt < 2; ++nt) {
            int j = nt * 16 + l15;
            float ang = (float)h * __expf(-(float)j * 0.28782313662425575f);  // ln(1e4)/32
            __sincosf(ang, &sn[nt], &cs[nt]);
        }
        ushort* C = (ushort*)Cv;
        #pragma unroll
        for (int m = 0; m < 4; ++m) {
            #pragma unroll
            for (int nt = 0; nt < 2; ++nt) {
                int col1 = n0 + wn * 64 + nt * 16 + l15;
                float b1v = bias[col1], b2v = bias[col1 + 32];
                #pragma unroll
                for (int r = 0; r < 4; ++r) {
                    int rowg = m0 + wm * 64 + m * 16 + quad * 4 + r;
                    float x1 = acc[m][nt][r] + b1v;
                    float x2 = acc[m][nt + 2][r] + b2v;
                    C[(size_t)rowg * E_ + col1]      = f2bf((x1 * cs[nt] - x2 * sn[nt]) * qsc);
                    C[(size_t)rowg * E_ + col1 + 32] = f2bf((x1 * sn[nt] + x2 * cs[nt]) * qsc);
                }
            }
        }
    }
}
#undef QSTA_
#undef QSTB_
#undef QLOAD_
#undef QMM_
#undef QPH_

// ------- 128x128 bf16 MFMA GEMM (V projection w/ fused V^T epilogue; out proj) -------
// DOVT: transpose the biased bf16 tile in reused smem (2 passes of 64 cols, pad 136)
// and write vt[(bh*64+d)][s] with coalesced 16B stores.
template<bool OUTF32, bool DOVT, int NZ>
__global__ __launch_bounds__(256) void gemm128(const ushort* __restrict__ A,
        const ushort* __restrict__ Bt0, const ushort* __restrict__ Bt1, const ushort* __restrict__ Bt2,
        const float* __restrict__ bias0, const float* __restrict__ bias1, const float* __restrict__ bias2,
        void* __restrict__ C0, void* __restrict__ C1, void* __restrict__ C2) {
    const int bid = blockIdx.x;
    const int z   = bid % NZ;
    const int nb  = (bid / NZ) % (E_ / 128);
    const int mb  = bid / (NZ * (E_ / 128));

    const ushort* Bt  = (z==0)?Bt0:(z==1)?Bt1:Bt2;
    const float* bias = (z==0)?bias0:(z==1)?bias1:bias2;
    void* Cv          = (z==0)?C0:(z==1)?C1:C2;

    __shared__ ushort smem[2 * 128 * 64];   // As | Bs; reused as transpose buffer
    ushort* As = smem;
    ushort* Bs = smem + 128 * 64;

    const int tid  = threadIdx.x;
    const int wave = tid >> 6, lane = tid & 63;
    const int quad = lane >> 4, l15 = lane & 15;
    const int wm = wave >> 1, wn = wave & 1;
    const int m0 = mb * 128, n0 = nb * 128;
    const int srow = tid >> 3;
    const int scgx = (tid & 7) ^ (srow & 7);   // swizzled source chunk

    f32x4 acc[4][4];
    #pragma unroll
    for (int i = 0; i < 4; ++i)
        #pragma unroll
        for (int j = 0; j < 4; ++j) acc[i][j] = f4zero();

    for (int k0 = 0; k0 < E_; k0 += 64) {
        #pragma unroll
        for (int it = 0; it < 4; ++it) {
            int r = it * 32 + srow;
            async16(A  + (size_t)(m0 + r) * E_ + k0 + scgx * 8, As + (it * 256 + wave * 64) * 8);
            async16(Bt + (size_t)(n0 + r) * E_ + k0 + scgx * 8, Bs + (it * 256 + wave * 64) * 8);
        }
        __syncthreads();
        #pragma unroll
        for (int kk = 0; kk < 2; ++kk) {
            bf16x8 af[4], bfr[4];
            #pragma unroll
            for (int mt = 0; mt < 4; ++mt) {
                int row = wm * 64 + mt * 16 + l15;
                af[mt] = *(const bf16x8*)(As + row * 64 + (((kk * 4 + quad) ^ (row & 7)) << 3));
            }
            #pragma unroll
            for (int nt = 0; nt < 4; ++nt) {
                int row = wn * 64 + nt * 16 + l15;
                bfr[nt] = *(const bf16x8*)(Bs + row * 64 + (((kk * 4 + quad) ^ (row & 7)) << 3));
            }
            #pragma unroll
            for (int mt = 0; mt < 4; ++mt)
                #pragma unroll
                for (int nt = 0; nt < 4; ++nt)
                    acc[mt][nt] = __builtin_amdgcn_mfma_f32_16x16x32_bf16(af[mt], bfr[nt], acc[mt][nt], 0, 0, 0);
        }
        __syncthreads();
    }

    if (DOVT) {
        // fused V^T: vt[(b*H + h)*64 + d][s] = acc + bias, via smem transpose
        ushort* tbuf = smem;                    // 64 x 136 ushorts = 17 KiB
        ushort* VT = (ushort*)Cv;
        const int b  = m0 >> 11;                // S_ = 2048
        const int s0 = m0 & (S_ - 1);
        #pragma unroll 1
        for (int p = 0; p < 2; ++p) {
            if (wn == p) {                      // 2 waves own this 64-col half
                #pragma unroll
                for (int mt = 0; mt < 4; ++mt)
                    #pragma unroll
                    for (int nt = 0; nt < 4; ++nt) {
                        int cl = nt * 16 + l15;                    // 0..63
                        float bv = bias[n0 + p * 64 + cl];
                        #pragma unroll
                        for (int r = 0; r < 4; ++r) {
                            int row = wm * 64 + mt * 16 + quad * 4 + r;  // 0..127
                            tbuf[cl * 136 + row] = f2bf(acc[mt][nt][r] + bv);
                        }
                    }
            }
            __syncthreads();
            {   // all 256 threads: d = tid>>2 (0..63), s-chunk = tid&3 (32 ush each)
                int d = tid >> 2, ch = tid & 3;
                int hh = (n0 + p * 64) >> 6;                       // head (tile-uniform)
                const ushort* src = tbuf + d * 136 + ch * 32;
                ushort* dst = VT + ((size_t)(b * H_ + hh) * 64 + d) * S_ + s0 + ch * 32;
                #pragma unroll
                for (int j = 0; j < 4; ++j)
                    *(uint4*)(dst + j * 8) = *(const uint4*)(src + j * 8);
            }
            __syncthreads();
        }
    } else {
        #pragma unroll
        for (int mt = 0; mt < 4; ++mt) {
            #pragma unroll
            for (int nt = 0; nt < 4; ++nt) {
                int col = n0 + wn * 64 + nt * 16 + l15;
                float bv = bias[col];
                #pragma unroll
                for (int r = 0; r < 4; ++r) {
                    int rowg = m0 + wm * 64 + mt * 16 + quad * 4 + r;
                    float v = acc[mt][nt][r] + bv;
                    if (OUTF32) ((float*)Cv)[(size_t)rowg * E_ + col] = v;
                    else        ((ushort*)Cv)[(size_t)rowg * E_ + col] = f2bf(v);
                }
            }
        }
    }
}

// ---------------- causal flash attention v7: 8 waves x 16 q-rows ----------------
// 512 threads (8 waves, 16 q-rows each); LDS 48KB -> 3 blocks/CU = 24 waves/CU.
// Raw v_exp_f32 (fexp2); wave-uniform diagonal-mask branch hoist.
// grid (8, B*H); block handles q-tiles {i, 15-i} (uniform 34 staged k-tiles).
__global__ __launch_bounds__(512) void flash_kernel(const ushort* __restrict__ qb,
        const ushort* __restrict__ kb, const ushort* __restrict__ vt,
        ushort* __restrict__ ctx) {
    __shared__ ushort KVs[2][2][64 * 64];   // [buf][K/V], swizzled   (32 KiB)
    __shared__ ushort Ps[8][16 * 64];       // per-wave P tile [q_local][s] (16 KiB)

    const int tid  = threadIdx.x;
    const int wave = tid >> 6, lane = tid & 63;
    const int quad = lane >> 4, l15 = lane & 15;
    const int bh = blockIdx.y, b = bh >> 5, h = bh & 31;
    const int srow = tid >> 3;                 // 0..63 (512 thr: full 64-row tile in 1 shot)
    const int scgx = (tid & 7) ^ (srow & 7);
    ushort* Pw = Ps[wave];

    bf16x8 ones;
    #pragma unroll
    for (int j = 0; j < 8; ++j) ones[j] = (__bf16)1.0f;

    #pragma unroll 1
    for (int pass = 0; pass < 2; ++pass) {
        const int qx  = pass ? (15 - (int)blockIdx.x) : (int)blockIdx.x;
        const int q0  = qx * 128;
        const int qw0 = q0 + wave * 16;        // this wave's 16 q-rows
        const int nkt = 2 * qx + 2;

        // Q fragments (B-operand of S^T mfma: lane l15 = q, k = kk*32+quad*8+j)
        bf16x8 qf[2];
        #pragma unroll
        for (int kk = 0; kk < 2; ++kk)
            qf[kk] = *(const bf16x8*)(qb + (size_t)(b * S_ + qw0 + l15) * E_ + h * 64 + kk * 32 + quad * 8);

        f32x4 oacc[4], lacc = f4zero();
        #pragma unroll
        for (int dt = 0; dt < 4; ++dt) oacc[dt] = f4zero();

        // stage tile 0 (one async16 per buffer: 512 thr cover 64 rows x 8 chunks)
        async16(kb + (size_t)(b * S_ + srow) * E_ + h * 64 + scgx * 8, KVs[0][0] + wave * 512);
        async16(vt + (size_t)(bh * 64 + srow) * S_ + scgx * 8,         KVs[0][1] + wave * 512);
        __syncthreads();

        #pragma unroll 1
        for (int kt = 0; kt < nkt; ++kt) {
            const int k0 = kt * 64;
            if (kt + 1 < nkt) {     // prefetch next tile into other buffer
                const int kn = k0 + 64;
                async16(kb + (size_t)(b * S_ + kn + srow) * E_ + h * 64 + scgx * 8,
                        KVs[(kt + 1) & 1][0] + wave * 512);
                async16(vt + (size_t)(bh * 64 + srow) * S_ + kn + scgx * 8,
                        KVs[(kt + 1) & 1][1] + wave * 512);
            }

            if (k0 <= qw0 + 15) {   // wave-uniform: skip fully-masked tiles
                const ushort* Ks = KVs[kt & 1][0];
                const ushort* Vs = KVs[kt & 1][1];
                f32x4 sacc[4];
                #pragma unroll
                for (int nt = 0; nt < 4; ++nt) sacc[nt] = f4zero();
                #pragma unroll
                for (int kk = 0; kk < 2; ++kk)
                    #pragma unroll
                    for (int nt = 0; nt < 4; ++nt) {
                        int row = nt * 16 + l15;
                        bf16x8 kf = *(const bf16x8*)(Ks + row * 64 + (((kk * 4 + quad) ^ (row & 7)) << 3));
                        sacc[nt] = __builtin_amdgcn_mfma_f32_16x16x32_bf16(kf, qf[kk], sacc[nt], 0, 0, 0);
                    }

                // fixed-max softmax, exp2 (log2e folded into Q); wave-uniform dm branch
                const bool dm = (k0 + 63 > qw0);
                const int swz = l15 & 7;
                if (dm) {
                    const int q = qw0 + l15;
                    #pragma unroll
                    for (int nt = 0; nt < 4; ++nt) {
                        float p[4];
                        #pragma unroll
                        for (int r = 0; r < 4; ++r) {
                            int s = k0 + nt * 16 + quad * 4 + r;
                            float e = fexp2(sacc[nt][r]);
                            p[r] = (s > q) ? 0.f : e;
                        }
                        uint2 pk;
                        pk.x = pack2bf(p[0], p[1]);
                        pk.y = pack2bf(p[2], p[3]);
                        *(uint2*)(Pw + l15 * 64 + (((nt * 2 + (quad >> 1)) ^ swz) << 3) + (quad & 1) * 4) = pk;
                    }
                } else {
                    #pragma unroll
                    for (int nt = 0; nt < 4; ++nt) {
                        uint2 pk;
                        pk.x = pack2bf(fexp2(sacc[nt][0]), fexp2(sacc[nt][1]));
                        pk.y = pack2bf(fexp2(sacc[nt][2]), fexp2(sacc[nt][3]));
                        *(uint2*)(Pw + l15 * 64 + (((nt * 2 + (quad >> 1)) ^ swz) << 3) + (quad & 1) * 4) = pk;
                    }
                }

                // O += P*V;  l += P*ones (row-sums in C-layout)
                #pragma unroll
                for (int kk = 0; kk < 2; ++kk) {
                    bf16x8 pf = *(const bf16x8*)(Pw + l15 * 64 + (((kk * 4 + quad) ^ swz) << 3));
                    lacc = __builtin_amdgcn_mfma_f32_16x16x32_bf16(pf, ones, lacc, 0, 0, 0);
                    #pragma unroll
                    for (int dt = 0; dt < 4; ++dt) {
                        int row = dt * 16 + l15;
                        bf16x8 vf = *(const bf16x8*)(Vs + row * 64 + (((kk * 4 + quad) ^ (row & 7)) << 3));
                        oacc[dt] = __builtin_amdgcn_mfma_f32_16x16x32_bf16(pf, vf, oacc[dt], 0, 0, 0);
                    }
                }
            }
            __syncthreads();   // drains prefetch after compute overlapped it; fences buf reuse
        }

        // epilogue: O C-layout row=quad*4+r (q), col=l15 (d); lacc rows align — no shuffles
        #pragma unroll
        for (int r = 0; r < 4; ++r) {
            float inv = 1.0f / lacc[r];
            #pragma unroll
            for (int dt = 0; dt < 4; ++dt)
                ctx[(size_t)(b * S_ + qw0 + quad * 4 + r) * E_ + h * 64 + dt * 16 + l15] =
                    f2bf(oacc[dt][r] * inv);
        }
    }
}

extern "C" void kernel_launch(void* const* d_in, const int* in_sizes, int n_in,
                              void* d_out, int out_size, void* d_ws, size_t ws_size,
                              hipStream_t stream) {
    const float* x  = (const float*)d_in[0];
    const float* Wq = (const float*)d_in[1];
    const float* bq = (const float*)d_in[2];
    const float* Wk = (const float*)d_in[3];
    const float* bk = (const float*)d_in[4];
    const float* Wv = (const float*)d_in[5];
    const float* bv = (const float*)d_in[6];
    const float* Wo = (const float*)d_in[7];
    const float* bo = (const float*)d_in[8];
    float* out = (float*)d_out;

    ushort* p   = (ushort*)d_ws;
    ushort* xb  = p; p += (size_t)M_ * E_;
    ushort* wqt = p; p += (size_t)E_ * E_;
    ushort* wkt = p; p += (size_t)E_ * E_;
    ushort* wvt = p; p += (size_t)E_ * E_;
    ushort* wot = p; p += (size_t)E_ * E_;
    ushort* qb  = p; p += (size_t)M_ * E_;
    ushort* kb  = p; p += (size_t)M_ * E_;
    ushort* vt  = p; p += (size_t)M_ * E_;   // V^T written directly by gemm128<DOVT>
    ushort* ctx = p; p += (size_t)M_ * E_;

    prep_kernel<<<NCAST + 4096, 256, 0, stream>>>(x, xb, Wq, Wk, Wv, Wo, wqt, wkt, wvt, wot);
    // Q+K: 128x256 read-ahead pipeline, grid = 32*8*2 = 512 blocks = exactly 2 generations
    gemm_qk<2><<<(M_ / 128) * (E_ / 256) * 2, 512, 0, stream>>>(
        xb, wqt, wkt, bq, bk, qb, kb);
    // V: 128x128 with fused V^T epilogue (writes vt directly)
    gemm128<false, true, 1><<<(E_ / 128) * (M_ / 128), 256, 0, stream>>>(
        xb, wvt, wvt, wvt, bv, bv, bv, vt, vt, vt);
    flash_kernel<<<dim3(8, B_ * H_), 512, 0, stream>>>(qb, kb, vt, ctx);
    gemm128<true, false, 1><<<(E_ / 128) * (M_ / 128), 256, 0, stream>>>(
        ctx, wot, wot, wot, bo, bo, bo, out, out, out);
}

// Round 10
// 358.887 us; speedup vs baseline: 1.0296x; 1.0296x over previous
//
#include <hip/hip_runtime.h>
#include <hip/hip_bf16.h>

#define B_ 2
#define S_ 2048
#define E_ 2048
#define H_ 32
#define M_ (B_*S_)   /* 4096 rows total */

typedef __bf16 bf16x8 __attribute__((ext_vector_type(8)));
typedef float  f32x4  __attribute__((ext_vector_type(4)));

__device__ __forceinline__ ushort f2bf(float f) {
    uint u = __float_as_uint(f);
    u += 0x7fffu + ((u >> 16) & 1u);   // RNE
    return (ushort)(u >> 16);
}
__device__ __forceinline__ uint pack2bf(float a, float b) {   // v_cvt_pk_bf16_f32
    __hip_bfloat162 h = __float22bfloat162_rn(make_float2(a, b));
    return *(uint*)&h;
}
__device__ __forceinline__ float fexp2(float x) {             // raw v_exp_f32
#if __has_builtin(__builtin_amdgcn_exp2f)
    return __builtin_amdgcn_exp2f(x);
#else
    return exp2f(x);
#endif
}
__device__ __forceinline__ f32x4 f4zero() {
    f32x4 z; z[0]=0.f; z[1]=0.f; z[2]=0.f; z[3]=0.f; return z;
}
// async global->LDS 16B: lds dest is wave-uniform base; HW scatters lane i to base+16*i
__device__ __forceinline__ void async16(const ushort* g, ushort* l) {
    __builtin_amdgcn_global_load_lds((const __attribute__((address_space(1))) void*)g,
                                     (__attribute__((address_space(3))) void*)l, 16, 0, 0);
}

// ---------- prep: cast x (f32->bf16) + transpose/cast 4 weights, one launch ----------
#define NCAST ((M_*E_)/1024)
__global__ __launch_bounds__(256) void prep_kernel(const float* __restrict__ x, ushort* __restrict__ xb,
        const float* __restrict__ W0, const float* __restrict__ W1,
        const float* __restrict__ W2, const float* __restrict__ W3,
        ushort* __restrict__ T0, ushort* __restrict__ T1,
        ushort* __restrict__ T2, ushort* __restrict__ T3) {
    const int bid = blockIdx.x;
    if (bid < NCAST) {              // ---- cast path: 4 f32 -> 4 bf16 per thread
        int i = (bid * 256 + threadIdx.x) * 4;
        float4 v = *(const float4*)(x + i);
        uint2 o;
        o.x = pack2bf(v.x, v.y);
        o.y = pack2bf(v.z, v.w);
        *(uint2*)(xb + i) = o;
        return;
    }
    // ---- wtrans path: W[k][n] f32 -> Wt[n][k] bf16
    const int wb = bid - NCAST;     // 0..4095
    const int z  = wb >> 10;
    const int rem = wb & 1023;
    const float* W = (z==0)?W0:(z==1)?W1:(z==2)?W2:W3;
    ushort*      T = (z==0)?T0:(z==1)?T1:(z==2)?T2:T3;
    __shared__ float tile[64][65];
    const int k0 = (rem >> 5) * 64, n0 = (rem & 31) * 64;
    const int rr = threadIdx.x >> 4;          // 0..15
    const int cc = (threadIdx.x & 15) * 4;    // 0..60
    #pragma unroll
    for (int p = 0; p < 4; ++p) {
        int r = p * 16 + rr;
        float4 v = *(const float4*)(W + (size_t)(k0 + r) * E_ + n0 + cc);
        tile[r][cc+0] = v.x; tile[r][cc+1] = v.y; tile[r][cc+2] = v.z; tile[r][cc+3] = v.w;
    }
    __syncthreads();
    #pragma unroll
    for (int p = 0; p < 4; ++p) {
        int rn = p * 16 + rr;
        uint2 o;
        o.x = pack2bf(tile[cc+0][rn], tile[cc+1][rn]);
        o.y = pack2bf(tile[cc+2][rn], tile[cc+3][rn]);
        *(uint2*)(T + (size_t)(n0 + rn) * E_ + k0 + cc) = o;
    }
}

// ============ 256x256 bf16 MFMA GEMM, 4 merged phases / 2 K-tiles (r8 proven) ============
// BM=BN=256, BK=64, 512 thr = 8 waves (2M x 4N), per-wave C = 128x64 (8x4 frags).
// Merged quadrant-phase pairs -> per phase: one A-half (pa, 8 reads) x FULL B
// (pb, 8 reads, held across the A1 phase) = 32 MFMA per barrier-pair.
// Stage ledger (WAR: each stage lands after its region's last-reader phase's
// closing lgkmcnt(0) fence; RAW: vmcnt(4) leaves exactly next tile's A0,B0
// 4 loads in flight, drains everything older):
//   PA:  T(2i+1).B1,A1 -> b1   PB:  T(2i+2).A0,B0 -> b0 + VMW4
//   PA': T(2i+2).B1,A1 -> b0   PB': T(2i+3).A0,B0 -> b1 + VMW4
// Chunk-XOR LDS swizzle via source permutation (0 bank conflicts, measured).
#define VMW4 asm volatile("s_waitcnt vmcnt(4)" ::: "memory")
#define VMW0 asm volatile("s_waitcnt vmcnt(0)" ::: "memory")
#define MEMB asm volatile("" ::: "memory")

#define STA_(bf, kt, h) { _Pragma("unroll") for (int it_ = 0; it_ < 2; ++it_) { \
    async16(A + (size_t)(m0 + it_*128 + (h)*64 + srow) * E_ + (kt)*64 + scg*8,  \
            &As[bf][(it_*128 + (h)*64 + wave*8) * 64]); } }

#define STB_(bf, kt, h) { _Pragma("unroll") for (int it_ = 0; it_ < 2; ++it_) { \
    int rih_ = it_*64 + srow;                                                   \
    int ldr_ = ((rih_ >> 5) << 6) + (h)*32 + (rih_ & 31);                       \
    int rwb_ = it_*64 + wave*8;                                                 \
    int wbs_ = ((rwb_ >> 5) << 6) + (h)*32 + (rwb_ & 31);                       \
    async16(Bt + (size_t)(n0 + ldr_) * E_ + (kt)*64 + scg*8,                    \
            &Bs[bf][wbs_ * 64]); } }

// One merged phase: load A-half mh (8 reads) [+ full B (8 reads) if LB], stage,
// barrier, 32 MFMA (compiler fine-grained lgkm waits), fence, barrier.
#define PH4_(bf, mh, LB, STAGES) {                                              \
    _Pragma("unroll") for (int m_ = 0; m_ < 4; ++m_)                            \
      _Pragma("unroll") for (int k_ = 0; k_ < 2; ++k_) {                        \
        int row_ = wm*128 + (mh)*64 + m_*16 + l15;                              \
        pa[m_][k_] = *(const bf16x8*)(&As[bf][row_*64 + (((k_*4 + quad) ^ (row_ & 7)) << 3)]); } \
    if (LB) {                                                                   \
      _Pragma("unroll") for (int n_ = 0; n_ < 4; ++n_)                          \
        _Pragma("unroll") for (int k_ = 0; k_ < 2; ++k_) {                      \
          int row_ = wn*64 + n_*16 + l15;                                       \
          pb[n_][k_] = *(const bf16x8*)(&Bs[bf][row_*64 + (((k_*4 + quad) ^ (row_ & 7)) << 3)]); } } \
    STAGES;                                                                     \
    MEMB; __builtin_amdgcn_s_barrier();                                         \
    __builtin_amdgcn_s_setprio(1);                                              \
    _Pragma("unroll") for (int k_ = 0; k_ < 2; ++k_)                            \
      _Pragma("unroll") for (int m_ = 0; m_ < 4; ++m_)                          \
        _Pragma("unroll") for (int n_ = 0; n_ < 4; ++n_)                        \
          acc[(mh)*4+m_][n_] = __builtin_amdgcn_mfma_f32_16x16x32_bf16(         \
              pa[m_][k_], pb[n_][k_], acc[(mh)*4+m_][n_], 0, 0, 0);             \
    __builtin_amdgcn_s_setprio(0);                                              \
    asm volatile("s_waitcnt lgkmcnt(0)" ::: "memory");                          \
    __builtin_amdgcn_sched_barrier(0);                                          \
    MEMB; __builtin_amdgcn_s_barrier(); MEMB;                                   \
  }

template<bool OUTF32, bool DOROPE, int NZ>
__global__ __launch_bounds__(512, 2) void gemm256(const ushort* __restrict__ A,
        const ushort* __restrict__ Bt0, const ushort* __restrict__ Bt1, const ushort* __restrict__ Bt2,
        const float* __restrict__ bias0, const float* __restrict__ bias1, const float* __restrict__ bias2,
        void* __restrict__ C0, void* __restrict__ C1, void* __restrict__ C2) {
    const int bid = blockIdx.x;
    const int z   = bid % NZ;                    // fastest: Q/K share A-tile
    const int nb  = (bid / NZ) % (E_ / 256);
    const int mb  = bid / (NZ * (E_ / 256));

    const ushort* Bt  = (z==0)?Bt0:(z==1)?Bt1:Bt2;
    const float* bias = (z==0)?bias0:(z==1)?bias1:bias2;
    void* Cv          = (z==0)?C0:(z==1)?C1:C2;

    __shared__ ushort As[2][256 * 64];   // 64 KiB
    __shared__ ushort Bs[2][256 * 64];   // 64 KiB

    const int tid  = threadIdx.x;
    const int wave = tid >> 6, lane = tid & 63;
    const int quad = lane >> 4, l15 = lane & 15;
    const int wm = wave >> 2, wn = wave & 3;
    const int m0 = mb * 256, n0 = nb * 256;
    const int srow = tid >> 3;                 // 0..63
    const int scg  = (tid & 7) ^ (srow & 7);   // swizzled source chunk

    f32x4 acc[8][4];
    #pragma unroll
    for (int i = 0; i < 8; ++i)
        #pragma unroll
        for (int j = 0; j < 4; ++j) acc[i][j] = f4zero();

    bf16x8 pa[4][2];   // current A-half
    bf16x8 pb[4][2];   // full B (held across the A1 phase)

    // prologue: T0 fully (8 loads), then T1.A0,B0 (4 in flight after vm4)
    STA_(0, 0, 0); STB_(0, 0, 0); STA_(0, 0, 1); STB_(0, 0, 1);
    STA_(1, 1, 0); STB_(1, 1, 0);
    VMW4;
    MEMB; __builtin_amdgcn_s_barrier(); MEMB;

    #pragma unroll 1
    for (int i = 0; i < 15; ++i) {
        const int t1 = 2*i + 1, t2 = 2*i + 2, t3 = 2*i + 3;
        PH4_(0, 0, 1, STB_(1, t1, 1); STA_(1, t1, 1));
        PH4_(0, 1, 0, STA_(0, t2, 0); STB_(0, t2, 0); VMW4);
        PH4_(1, 0, 1, STB_(0, t2, 1); STA_(0, t2, 1));
        PH4_(1, 1, 0, STA_(1, t3, 0); STB_(1, t3, 0); VMW4);
    }
    // peeled last window: tiles 30 (buf0), 31 (buf1)
    PH4_(0, 0, 1, STB_(1, 31, 1); STA_(1, 31, 1));
    PH4_(0, 1, 0, VMW0);
    PH4_(1, 0, 1, {});
    PH4_(1, 1, 0, {});

    if (DOROPE && z != 2) {
        // head-wise RoPE: head = col/64 wave-uniform; x1=acc[f][nt], x2=acc[f][nt+2]
        const float qsc = (z == 0) ? 0.125f * 1.44269504f : 1.0f;  // fold log2e
        const int h = (n0 + wn * 64) >> 6;
        float sn[2], cs[2];
        #pragma unroll
        for (int nt = 0; nt < 2; ++nt) {
            int j = nt * 16 + l15;
            float ang = (float)h * __expf(-(float)j * 0.28782313662425575f);  // ln(1e4)/32
            __sincosf(ang, &sn[nt], &cs[nt]);
        }
        ushort* C = (ushort*)Cv;
        #pragma unroll
        for (int f = 0; f < 8; ++f) {
            #pragma unroll
            for (int nt = 0; nt < 2; ++nt) {
                int col1 = n0 + wn * 64 + nt * 16 + l15;
                float b1 = bias[col1], b2 = bias[col1 + 32];
                #pragma unroll
                for (int r = 0; r < 4; ++r) {
                    int rowg = m0 + wm * 128 + f * 16 + quad * 4 + r;
                    float x1 = acc[f][nt][r] + b1;
                    float x2 = acc[f][nt + 2][r] + b2;
                    C[(size_t)rowg * E_ + col1]      = f2bf((x1 * cs[nt] - x2 * sn[nt]) * qsc);
                    C[(size_t)rowg * E_ + col1 + 32] = f2bf((x1 * sn[nt] + x2 * cs[nt]) * qsc);
                }
            }
        }
    } else {
        #pragma unroll
        for (int f = 0; f < 8; ++f) {
            #pragma unroll
            for (int nt = 0; nt < 4; ++nt) {
                int col = n0 + wn * 64 + nt * 16 + l15;
                float bv = bias[col];
                #pragma unroll
                for (int r = 0; r < 4; ++r) {
                    int rowg = m0 + wm * 128 + f * 16 + quad * 4 + r;
                    float v = acc[f][nt][r] + bv;
                    if (OUTF32) ((float*)Cv)[(size_t)rowg * E_ + col] = v;
                    else        ((ushort*)Cv)[(size_t)rowg * E_ + col] = f2bf(v);
                }
            }
        }
    }
}
#undef STA_
#undef STB_
#undef PH4_

// ------- 128x128 bf16 MFMA GEMM (V projection w/ fused V^T epilogue; out proj) -------
// DOVT: transpose the biased bf16 tile in reused smem (2 passes of 64 cols, pad 136)
// and write vt[(bh*64+d)][s] with coalesced 16B stores.
template<bool OUTF32, bool DOVT, int NZ>
__global__ __launch_bounds__(256) void gemm128(const ushort* __restrict__ A,
        const ushort* __restrict__ Bt0, const ushort* __restrict__ Bt1, const ushort* __restrict__ Bt2,
        const float* __restrict__ bias0, const float* __restrict__ bias1, const float* __restrict__ bias2,
        void* __restrict__ C0, void* __restrict__ C1, void* __restrict__ C2) {
    const int bid = blockIdx.x;
    const int z   = bid % NZ;
    const int nb  = (bid / NZ) % (E_ / 128);
    const int mb  = bid / (NZ * (E_ / 128));

    const ushort* Bt  = (z==0)?Bt0:(z==1)?Bt1:Bt2;
    const float* bias = (z==0)?bias0:(z==1)?bias1:bias2;
    void* Cv          = (z==0)?C0:(z==1)?C1:C2;

    __shared__ ushort smem[2 * 128 * 64];   // As | Bs; reused as transpose buffer
    ushort* As = smem;
    ushort* Bs = smem + 128 * 64;

    const int tid  = threadIdx.x;
    const int wave = tid >> 6, lane = tid & 63;
    const int quad = lane >> 4, l15 = lane & 15;
    const int wm = wave >> 1, wn = wave & 1;
    const int m0 = mb * 128, n0 = nb * 128;
    const int srow = tid >> 3;
    const int scgx = (tid & 7) ^ (srow & 7);   // swizzled source chunk

    f32x4 acc[4][4];
    #pragma unroll
    for (int i = 0; i < 4; ++i)
        #pragma unroll
        for (int j = 0; j < 4; ++j) acc[i][j] = f4zero();

    for (int k0 = 0; k0 < E_; k0 += 64) {
        #pragma unroll
        for (int it = 0; it < 4; ++it) {
            int r = it * 32 + srow;
            async16(A  + (size_t)(m0 + r) * E_ + k0 + scgx * 8, As + (it * 256 + wave * 64) * 8);
            async16(Bt + (size_t)(n0 + r) * E_ + k0 + scgx * 8, Bs + (it * 256 + wave * 64) * 8);
        }
        __syncthreads();
        #pragma unroll
        for (int kk = 0; kk < 2; ++kk) {
            bf16x8 af[4], bfr[4];
            #pragma unroll
            for (int mt = 0; mt < 4; ++mt) {
                int row = wm * 64 + mt * 16 + l15;
                af[mt] = *(const bf16x8*)(As + row * 64 + (((kk * 4 + quad) ^ (row & 7)) << 3));
            }
            #pragma unroll
            for (int nt = 0; nt < 4; ++nt) {
                int row = wn * 64 + nt * 16 + l15;
                bfr[nt] = *(const bf16x8*)(Bs + row * 64 + (((kk * 4 + quad) ^ (row & 7)) << 3));
            }
            #pragma unroll
            for (int mt = 0; mt < 4; ++mt)
                #pragma unroll
                for (int nt = 0; nt < 4; ++nt)
                    acc[mt][nt] = __builtin_amdgcn_mfma_f32_16x16x32_bf16(af[mt], bfr[nt], acc[mt][nt], 0, 0, 0);
        }
        __syncthreads();
    }

    if (DOVT) {
        // fused V^T: vt[(b*H + h)*64 + d][s] = acc + bias, via smem transpose
        ushort* tbuf = smem;                    // 64 x 136 ushorts = 17 KiB
        ushort* VT = (ushort*)Cv;
        const int b  = m0 >> 11;                // S_ = 2048
        const int s0 = m0 & (S_ - 1);
        #pragma unroll 1
        for (int p = 0; p < 2; ++p) {
            if (wn == p) {                      // 2 waves own this 64-col half
                #pragma unroll
                for (int mt = 0; mt < 4; ++mt)
                    #pragma unroll
                    for (int nt = 0; nt < 4; ++nt) {
                        int cl = nt * 16 + l15;                    // 0..63
                        float bv = bias[n0 + p * 64 + cl];
                        #pragma unroll
                        for (int r = 0; r < 4; ++r) {
                            int row = wm * 64 + mt * 16 + quad * 4 + r;  // 0..127
                            tbuf[cl * 136 + row] = f2bf(acc[mt][nt][r] + bv);
                        }
                    }
            }
            __syncthreads();
            {   // all 256 threads: d = tid>>2 (0..63), s-chunk = tid&3 (32 ush each)
                int d = tid >> 2, ch = tid & 3;
                int hh = (n0 + p * 64) >> 6;                       // head (tile-uniform)
                const ushort* src = tbuf + d * 136 + ch * 32;
                ushort* dst = VT + ((size_t)(b * H_ + hh) * 64 + d) * S_ + s0 + ch * 32;
                #pragma unroll
                for (int j = 0; j < 4; ++j)
                    *(uint4*)(dst + j * 8) = *(const uint4*)(src + j * 8);
            }
            __syncthreads();
        }
    } else {
        #pragma unroll
        for (int mt = 0; mt < 4; ++mt) {
            #pragma unroll
            for (int nt = 0; nt < 4; ++nt) {
                int col = n0 + wn * 64 + nt * 16 + l15;
                float bv = bias[col];
                #pragma unroll
                for (int r = 0; r < 4; ++r) {
                    int rowg = m0 + wm * 64 + mt * 16 + quad * 4 + r;
                    float v = acc[mt][nt][r] + bv;
                    if (OUTF32) ((float*)Cv)[(size_t)rowg * E_ + col] = v;
                    else        ((ushort*)Cv)[(size_t)rowg * E_ + col] = f2bf(v);
                }
            }
        }
    }
}

// ---------------- causal flash attention v8: XCD-local head grouping ----------------
// r9 change: 1D grid 512, decode bh = bid & 63 (FAST), qx = bid >> 6. The 8 blocks
// sharing one head's K/V get linear ids == bh (mod 8) -> same XCD (dispatch
// round-robins XCDs by linear id). 8 heads/XCD x 512KB K/V = 4MB = one L2: K/V
// re-reads become L2 hits (r5 FETCH 147MB ~= 4.5x ideal was this effect).
// 512 threads (8 waves x 16 q-rows); LDS 48KB; raw v_exp_f32; uniform dm hoist.
__global__ __launch_bounds__(512) void flash_kernel(const ushort* __restrict__ qb,
        const ushort* __restrict__ kb, const ushort* __restrict__ vt,
        ushort* __restrict__ ctx) {
    __shared__ ushort KVs[2][2][64 * 64];   // [buf][K/V], swizzled   (32 KiB)
    __shared__ ushort Ps[8][16 * 64];       // per-wave P tile [q_local][s] (16 KiB)

    const int tid  = threadIdx.x;
    const int wave = tid >> 6, lane = tid & 63;
    const int quad = lane >> 4, l15 = lane & 15;
    const int bh = blockIdx.x & 63;            // FAST index -> same-head blocks co-XCD
    const int qxb = blockIdx.x >> 6;           // 0..7
    const int b = bh >> 5, h = bh & 31;
    const int srow = tid >> 3;                 // 0..63 (512 thr: full 64-row tile in 1 shot)
    const int scgx = (tid & 7) ^ (srow & 7);
    ushort* Pw = Ps[wave];

    bf16x8 ones;
    #pragma unroll
    for (int j = 0; j < 8; ++j) ones[j] = (__bf16)1.0f;

    #pragma unroll 1
    for (int pass = 0; pass < 2; ++pass) {
        const int qx  = pass ? (15 - qxb) : qxb;
        const int q0  = qx * 128;
        const int qw0 = q0 + wave * 16;        // this wave's 16 q-rows
        const int nkt = 2 * qx + 2;

        // Q fragments (B-operand of S^T mfma: lane l15 = q, k = kk*32+quad*8+j)
        bf16x8 qf[2];
        #pragma unroll
        for (int kk = 0; kk < 2; ++kk)
            qf[kk] = *(const bf16x8*)(qb + (size_t)(b * S_ + qw0 + l15) * E_ + h * 64 + kk * 32 + quad * 8);

        f32x4 oacc[4], lacc = f4zero();
        #pragma unroll
        for (int dt = 0; dt < 4; ++dt) oacc[dt] = f4zero();

        // stage tile 0 (one async16 per buffer: 512 thr cover 64 rows x 8 chunks)
        async16(kb + (size_t)(b * S_ + srow) * E_ + h * 64 + scgx * 8, KVs[0][0] + wave * 512);
        async16(vt + (size_t)(bh * 64 + srow) * S_ + scgx * 8,         KVs[0][1] + wave * 512);
        __syncthreads();

        #pragma unroll 1
        for (int kt = 0; kt < nkt; ++kt) {
            const int k0 = kt * 64;
            if (kt + 1 < nkt) {     // prefetch next tile into other buffer
                const int kn = k0 + 64;
                async16(kb + (size_t)(b * S_ + kn + srow) * E_ + h * 64 + scgx * 8,
                        KVs[(kt + 1) & 1][0] + wave * 512);
                async16(vt + (size_t)(bh * 64 + srow) * S_ + kn + scgx * 8,
                        KVs[(kt + 1) & 1][1] + wave * 512);
            }

            if (k0 <= qw0 + 15) {   // wave-uniform: skip fully-masked tiles
                const ushort* Ks = KVs[kt & 1][0];
                const ushort* Vs = KVs[kt & 1][1];
                f32x4 sacc[4];
                #pragma unroll
                for (int nt = 0; nt < 4; ++nt) sacc[nt] = f4zero();
                #pragma unroll
                for (int kk = 0; kk < 2; ++kk)
                    #pragma unroll
                    for (int nt = 0; nt < 4; ++nt) {
                        int row = nt * 16 + l15;
                        bf16x8 kf = *(const bf16x8*)(Ks + row * 64 + (((kk * 4 + quad) ^ (row & 7)) << 3));
                        sacc[nt] = __builtin_amdgcn_mfma_f32_16x16x32_bf16(kf, qf[kk], sacc[nt], 0, 0, 0);
                    }

                // fixed-max softmax, exp2 (log2e folded into Q); wave-uniform dm branch
                const bool dm = (k0 + 63 > qw0);
                const int swz = l15 & 7;
                if (dm) {
                    const int q = qw0 + l15;
                    #pragma unroll
                    for (int nt = 0; nt < 4; ++nt) {
                        float p[4];
                        #pragma unroll
                        for (int r = 0; r < 4; ++r) {
                            int s = k0 + nt * 16 + quad * 4 + r;
                            float e = fexp2(sacc[nt][r]);
                            p[r] = (s > q) ? 0.f : e;
                        }
                        uint2 pk;
                        pk.x = pack2bf(p[0], p[1]);
                        pk.y = pack2bf(p[2], p[3]);
                        *(uint2*)(Pw + l15 * 64 + (((nt * 2 + (quad >> 1)) ^ swz) << 3) + (quad & 1) * 4) = pk;
                    }
                } else {
                    #pragma unroll
                    for (int nt = 0; nt < 4; ++nt) {
                        uint2 pk;
                        pk.x = pack2bf(fexp2(sacc[nt][0]), fexp2(sacc[nt][1]));
                        pk.y = pack2bf(fexp2(sacc[nt][2]), fexp2(sacc[nt][3]));
                        *(uint2*)(Pw + l15 * 64 + (((nt * 2 + (quad >> 1)) ^ swz) << 3) + (quad & 1) * 4) = pk;
                    }
                }

                // O += P*V;  l += P*ones (row-sums in C-layout)
                #pragma unroll
                for (int kk = 0; kk < 2; ++kk) {
                    bf16x8 pf = *(const bf16x8*)(Pw + l15 * 64 + (((kk * 4 + quad) ^ swz) << 3));
                    lacc = __builtin_amdgcn_mfma_f32_16x16x32_bf16(pf, ones, lacc, 0, 0, 0);
                    #pragma unroll
                    for (int dt = 0; dt < 4; ++dt) {
                        int row = dt * 16 + l15;
                        bf16x8 vf = *(const bf16x8*)(Vs + row * 64 + (((kk * 4 + quad) ^ (row & 7)) << 3));
                        oacc[dt] = __builtin_amdgcn_mfma_f32_16x16x32_bf16(pf, vf, oacc[dt], 0, 0, 0);
                    }
                }
            }
            __syncthreads();   // drains prefetch after compute overlapped it; fences buf reuse
        }

        // epilogue: O C-layout row=quad*4+r (q), col=l15 (d); lacc rows align — no shuffles
        #pragma unroll
        for (int r = 0; r < 4; ++r) {
            float inv = 1.0f / lacc[r];
            #pragma unroll
            for (int dt = 0; dt < 4; ++dt)
                ctx[(size_t)(b * S_ + qw0 + quad * 4 + r) * E_ + h * 64 + dt * 16 + l15] =
                    f2bf(oacc[dt][r] * inv);
        }
    }
}

extern "C" void kernel_launch(void* const* d_in, const int* in_sizes, int n_in,
                              void* d_out, int out_size, void* d_ws, size_t ws_size,
                              hipStream_t stream) {
    const float* x  = (const float*)d_in[0];
    const float* Wq = (const float*)d_in[1];
    const float* bq = (const float*)d_in[2];
    const float* Wk = (const float*)d_in[3];
    const float* bk = (const float*)d_in[4];
    const float* Wv = (const float*)d_in[5];
    const float* bv = (const float*)d_in[6];
    const float* Wo = (const float*)d_in[7];
    const float* bo = (const float*)d_in[8];
    float* out = (float*)d_out;

    ushort* p   = (ushort*)d_ws;
    ushort* xb  = p; p += (size_t)M_ * E_;
    ushort* wqt = p; p += (size_t)E_ * E_;
    ushort* wkt = p; p += (size_t)E_ * E_;
    ushort* wvt = p; p += (size_t)E_ * E_;
    ushort* wot = p; p += (size_t)E_ * E_;
    ushort* qb  = p; p += (size_t)M_ * E_;
    ushort* kb  = p; p += (size_t)M_ * E_;
    ushort* vt  = p; p += (size_t)M_ * E_;   // V^T written directly by gemm128<DOVT>
    ushort* ctx = p; p += (size_t)M_ * E_;

    prep_kernel<<<NCAST + 4096, 256, 0, stream>>>(x, xb, Wq, Wk, Wv, Wo, wqt, wkt, wvt, wot);
    // Q+K: 256x256 4-phase, grid = 2*8*16 = 256 blocks = exactly 1 generation (no tail)
    gemm256<false, true, 2><<<(E_ / 256) * (M_ / 256) * 2, 512, 0, stream>>>(
        xb, wqt, wkt, wkt, bq, bk, bk, qb, kb, kb);
    // V: 128x128 with fused V^T epilogue (writes vt directly)
    gemm128<false, true, 1><<<(E_ / 128) * (M_ / 128), 256, 0, stream>>>(
        xb, wvt, wvt, wvt, bv, bv, bv, vt, vt, vt);
    // flash: 1D grid, bh-fastest for XCD-local K/V reuse
    flash_kernel<<<8 * B_ * H_, 512, 0, stream>>>(qb, kb, vt, ctx);
    gemm128<true, false, 1><<<(E_ / 128) * (M_ / 128), 256, 0, stream>>>(
        ctx, wot, wot, wot, bo, bo, bo, out, out, out);
}